// Round 6
// baseline (251.032 us; speedup 1.0000x reference)
//
#include <hip/hip_runtime.h>
#include <hip/hip_bf16.h>

#define NB 4
#define CCH 256
#define CRD 32
#define NN 4096

typedef __attribute__((ext_vector_type(8))) short short8;
typedef __attribute__((ext_vector_type(4))) short short4v;
typedef __attribute__((ext_vector_type(4))) float floatx4;
typedef __attribute__((ext_vector_type(4))) int intx4;
typedef __attribute__((ext_vector_type(2))) unsigned int uintx2;

__device__ __forceinline__ unsigned short f2bf(float f) {
  unsigned u = __builtin_bit_cast(unsigned, f);
  u += 0x7FFFu + ((u >> 16) & 1u);
  return (unsigned short)(u >> 16);
}

// Clamped convert: finite bf16 regardless of input (NaN -> -1e4 via IEEE
// maxNum/minNum, +-inf -> +-1e4). Legit qkv values |v| < ~20: transparent.
__device__ __forceinline__ unsigned short f2bf_c(float f) {
  f = fminf(fmaxf(f, -1.0e4f), 1.0e4f);
  unsigned u = __builtin_bit_cast(unsigned, f);
  u += 0x7FFFu + ((u >> 16) & 1u);
  return (unsigned short)(u >> 16);
}

__device__ __forceinline__ unsigned pack2c(float a, float b) {
  return (unsigned)f2bf_c(a) | ((unsigned)f2bf_c(b) << 16);
}

// Output sanitizer: NaN -> -1e30 (IEEE maxNum), +-inf -> +-1e30.
__device__ __forceinline__ float sat(float v) {
  return fminf(fmaxf(v, -1.0e30f), 1.0e30f);
}

__device__ __forceinline__ short8 ld_frag_g(const unsigned short* p) {
  return __builtin_bit_cast(short8, *(const intx4*)p);
}

__device__ __forceinline__ void st8(void* p, int a, int b) {
  uintx2 u; u[0] = (unsigned)a; u[1] = (unsigned)b;
  *(uintx2*)p = u;
}

// K=16 bf16 MFMA: D[m=lq*4+e][n=lm] += A[m=lm][k=lq*4+e] * B[k=lq*4+e][n=lm]
__device__ __forceinline__ floatx4 mfma16(short4v a, short4v b, floatx4 c) {
#if __has_builtin(__builtin_amdgcn_mfma_f32_16x16x16bf16_1k)
  return __builtin_amdgcn_mfma_f32_16x16x16bf16_1k(a, b, c, 0, 0, 0);
#else
  asm("v_mfma_f32_16x16x16_bf16 %0, %1, %2, %0" : "+v"(c) : "v"(a), "v"(b));
  return c;
#endif
}

// ---------------------------------------------------------------------------
// Kernel 1: fused transpose + QKV GEMM (unchanged; stable since round 2).
// ---------------------------------------------------------------------------
__global__ __launch_bounds__(256) void gemm_qkv_fused(
    const float* __restrict__ x,
    const float* __restrict__ Wq, const float* __restrict__ bq,
    const float* __restrict__ Wk, const float* __restrict__ bk,
    const float* __restrict__ Wv, const float* __restrict__ bv,
    unsigned short* __restrict__ qT, unsigned short* __restrict__ kT,
    unsigned short* __restrict__ vv)
{
  __shared__ __align__(16) unsigned short xs[64 * 264];
  __shared__ __align__(16) unsigned short ws[64 * 264];

  const int tid  = threadIdx.x;
  const int wave = tid >> 6;
  const int lane = tid & 63;
  const int lq   = lane >> 4;
  const int lm   = lane & 15;
  const int n0   = blockIdx.x << 6;
  const int mg   = blockIdx.y;
  const int b    = blockIdx.z;

  {
    const int nn = lane;
    const int cg = wave;
    const float* xb = x + ((size_t)b << 20) + n0 + nn;
#pragma unroll
    for (int it = 0; it < 16; ++it) {
      const int c0 = it * 16 + cg * 4;
      const float v0 = xb[(size_t)(c0 + 0) << 12];
      const float v1 = xb[(size_t)(c0 + 1) << 12];
      const float v2 = xb[(size_t)(c0 + 2) << 12];
      const float v3 = xb[(size_t)(c0 + 3) << 12];
      uintx2 u;
      u[0] = pack2c(v0, v1);
      u[1] = pack2c(v2, v3);
      *(uintx2*)(xs + nn * 264 + c0) = u;
    }
  }

  const int mt_lo = mg ? 3 : 0;
  const int mt_hi = mg ? 5 : 3;

  for (int mt = mt_lo; mt < mt_hi; ++mt) {
#pragma unroll
    for (int i = 0; i < 16; ++i) {
      const int u  = i * 256 + tid;
      const int m  = u >> 6;
      const int o4 = (u & 63) * 4;
      const float* src = (mt == 0)
          ? (m < 32 ? Wq + (size_t)m * CCH : Wk + (size_t)(m - 32) * CCH)
          : Wv + (size_t)((mt - 1) * 64 + m) * CCH;
      const floatx4 f = *(const floatx4*)(src + o4);
      uintx2 uu;
      uu[0] = pack2c(f[0], f[1]);
      uu[1] = pack2c(f[2], f[3]);
      *(uintx2*)(ws + m * 264 + o4) = uu;
    }
    __syncthreads();

    floatx4 acc[4];
#pragma unroll
    for (int t = 0; t < 4; ++t) acc[t] = (floatx4){0.f, 0.f, 0.f, 0.f};

#pragma unroll
    for (int k0 = 0; k0 < 8; ++k0) {
      short8 af[4];
#pragma unroll
      for (int ms = 0; ms < 4; ++ms)
        af[ms] = __builtin_bit_cast(short8,
            *(const intx4*)(ws + (ms * 16 + lm) * 264 + k0 * 32 + lq * 8));
      const short8 bf = __builtin_bit_cast(short8,
          *(const intx4*)(xs + (wave * 16 + lm) * 264 + k0 * 32 + lq * 8));
#pragma unroll
      for (int ms = 0; ms < 4; ++ms)
        acc[ms] = __builtin_amdgcn_mfma_f32_16x16x32_bf16(af[ms], bf,
                                                          acc[ms], 0, 0, 0);
    }
    __syncthreads();

    if (mt == 0) {
      const int n = n0 + wave * 16 + lm;
#pragma unroll
      for (int ms = 0; ms < 4; ++ms) {
        const int d0 = (ms & 1) * 16 + lq * 4;
        const float* bias = (ms < 2) ? bq : bk;
        unsigned short* dst = (ms < 2) ? qT : kT;
        uintx2 u;
        u[0] = pack2c(acc[ms][0] + bias[d0],     acc[ms][1] + bias[d0 + 1]);
        u[1] = pack2c(acc[ms][2] + bias[d0 + 2], acc[ms][3] + bias[d0 + 3]);
        *(uintx2*)(dst + (size_t)(b * NN + n) * CRD + d0) = u;
      }
    } else {
      const int cb = (mt - 1) * 64;
      unsigned short* vb2 = ws;
#pragma unroll
      for (int ms = 0; ms < 4; ++ms)
#pragma unroll
        for (int r = 0; r < 4; ++r) {
          const int c = ms * 16 + lq * 4 + r;
          vb2[c * 64 + wave * 16 + lm] = f2bf_c(acc[ms][r] + bv[cb + c]);
        }
      __syncthreads();
#pragma unroll
      for (int it = 0; it < 2; ++it) {
        const int u = it * 256 + tid;
        const int m = u >> 3;
        const int o = (u & 7) * 8;
        *(intx4*)(vv + (size_t)(b * CCH + cb + m) * NN + n0 + o) =
            *(const intx4*)(vb2 + m * 64 + o);
      }
      __syncthreads();
    }
  }
}

// ---------------------------------------------------------------------------
// Kernel 2: attention, round-17.
//   Register-resident P^T (r5 mechanism, proven) with the redundancy cut
//   back to 2x (r1's VALU level): block = 512 thr / 32 i-rows; 8 waves =
//   4 j-slabs (16 j, jw) x 2 c-halves (128 c, ch). Window 64 j, 64 iters,
//   ONE barrier per iter (V double-buffer).
//   QK: S^T = mfma_16x16x32(K_frag, Q_frag) -> D[j=lq*4+r][i=lm].
//   PV: K=16 mfma_16x16x16: B-frag B[k=lq*4+e][n=lm] == S^T frag layout
//   EXACTLY -> P stays in registers, no permutation, no LDS round-trip.
//   V A-frag: A[c=lm][j=lq*4+e] = plain 8B LDS read, granule-XOR swizzled.
//   acc = 128c x 32i = 16 frags = 64 VGPR (r4's 128-VGPR blowup avoided).
//   Final: 4-way j-slab reduce via 32KB LDS overlay + coalesced epilogue.
// ---------------------------------------------------------------------------
__global__ __launch_bounds__(512) void attn_kernel(
    const float* __restrict__ x, const float* __restrict__ gamma_p,
    const unsigned short* __restrict__ qT, const unsigned short* __restrict__ kT,
    const unsigned short* __restrict__ vv, float* __restrict__ out)
{
  // [0, 65536): V double buffer, 2 x [256 c][64 j] bf16 (128 B/row, swizzled)
  // [65536, +512): lsumlds float[4][32]; [66048, +128): invlds float[32]
  __shared__ __align__(16) unsigned char smem[66176];

  const int tid  = threadIdx.x;
  const int wave = tid >> 6;
  const int jw   = wave & 3;    // j-slab 0..3 (16 j of the 64-window)
  const int ch   = wave >> 2;   // c-half 0..1 (128 c)
  const int lane = tid & 63;
  const int lq   = lane >> 4;
  const int lm   = lane & 15;
  const int xcd  = blockIdx.x & 7;
  const int pos  = blockIdx.x >> 3;              // 0..63
  const int b    = xcd >> 1;
  const int i0   = (((xcd & 1) << 6) | pos) << 5;   // 32-row i-block

  const unsigned short* kTb = kT + (size_t)b * NN * CRD;
  const unsigned short* vb  = vv + (size_t)b * CCH * NN;

  // Q B-frags (for QK): B[d=lq*8+e][i=lm], 2 i-tiles
  short8 qf[2];
#pragma unroll
  for (int f = 0; f < 2; ++f)
    qf[f] = ld_frag_g(qT + (size_t)(b * NN + i0 + f * 16 + lm) * CRD + lq * 8);

  // V staging coords: unit u = m*512+tid; c = u>>3, j0 = (u&7)*8 (16B load).
  // LDS row c: 16 8-byte granules; granule g stored at g ^ (c&15).
  int g_off[4], l_off1[4], l_off2[4];
#pragma unroll
  for (int m = 0; m < 4; ++m) {
    const int u  = m * 512 + tid;
    const int c  = u >> 3;
    const int j0 = (u & 7) * 8;
    g_off[m] = c * NN + j0;
    const int g0 = j0 >> 2;                       // even granule
    l_off1[m] = c * 128 + (((g0    ) ^ (c & 15)) << 3);
    l_off2[m] = c * 128 + (((g0 + 1) ^ (c & 15)) << 3);
  }

  floatx4 acc[8][2];                              // [cf][f] = 64 VGPR
#pragma unroll
  for (int cf = 0; cf < 8; ++cf)
#pragma unroll
    for (int f = 0; f < 2; ++f) acc[cf][f] = (floatx4){0.f, 0.f, 0.f, 0.f};
  float lsum[2] = {0.f, 0.f};

  // prologue: window 0 -> LDS parity 0; vreg <- window 1; kf <- window 0 slab
  intx4 vreg[4];
#pragma unroll
  for (int m = 0; m < 4; ++m)
    vreg[m] = *(const intx4*)(vb + g_off[m]);
#pragma unroll
  for (int m = 0; m < 4; ++m) {
    st8(smem + l_off1[m], vreg[m][0], vreg[m][1]);
    st8(smem + l_off2[m], vreg[m][2], vreg[m][3]);
  }
#pragma unroll
  for (int m = 0; m < 4; ++m)
    vreg[m] = *(const intx4*)(vb + g_off[m] + 64);
  short8 kf[2];
  kf[0] = ld_frag_g(kTb + (size_t)(jw * 16 + lm) * CRD + lq * 8);

  const floatx4 zf = {0.f, 0.f, 0.f, 0.f};

#pragma unroll 2
  for (int k = 0; k < 64; ++k) {
    // barrier: V(k) writes (iter k-1) visible; PV(k-1) reads all complete
    __syncthreads();
    unsigned char* vbp = smem + ((k & 1) << 15);        // read V(k)
    unsigned char* vbn = smem + (((k + 1) & 1) << 15);  // write V(k+1)

    if (k < 63) {
#pragma unroll
      for (int m = 0; m < 4; ++m) {
        st8(vbn + l_off1[m], vreg[m][0], vreg[m][1]);
        st8(vbn + l_off2[m], vreg[m][2], vreg[m][3]);
      }
    }
    if (k < 62) {
      const int jg = (k + 2) << 6;
#pragma unroll
      for (int m = 0; m < 4; ++m)
        vreg[m] = *(const intx4*)(vb + g_off[m] + jg);
    }

    // S^T = K Q^T for this wave's 16-j slab; exp; pack -> PV B-frags (regs)
    short4v pf[2];
#pragma unroll
    for (int f = 0; f < 2; ++f) {
      const floatx4 S = __builtin_amdgcn_mfma_f32_16x16x32_bf16(
          kf[k & 1], qf[f], zf, 0, 0, 0);
      const float p0 = __expf(fminf(fmaxf(S[0], -40.f), 40.f));
      const float p1 = __expf(fminf(fmaxf(S[1], -40.f), 40.f));
      const float p2 = __expf(fminf(fmaxf(S[2], -40.f), 40.f));
      const float p3 = __expf(fminf(fmaxf(S[3], -40.f), 40.f));
      lsum[f] += (p0 + p1) + (p2 + p3);
      uintx2 u;
      u[0] = (unsigned)f2bf(p0) | ((unsigned)f2bf(p1) << 16);
      u[1] = (unsigned)f2bf(p2) | ((unsigned)f2bf(p3) << 16);
      pf[f] = __builtin_bit_cast(short4v, u);
    }

    // K slab prefetch for window k+1
    if (k < 63) {
      const int jn = (k + 1) << 6;
      kf[(k + 1) & 1] =
          ld_frag_g(kTb + (size_t)(jn + jw * 16 + lm) * CRD + lq * 8);
    }

    // PV: acc[c][i] += V[c][j] * P^T[j][i] over this slab's 16 j (K=16)
    __builtin_amdgcn_s_setprio(1);
#pragma unroll
    for (int cf = 0; cf < 8; ++cf) {
      const int c = ch * 128 + cf * 16 + lm;
      const short4v vf = *(const short4v*)(
          vbp + c * 128 + (((jw * 4 + lq) ^ (c & 15)) << 3));
#pragma unroll
      for (int f = 0; f < 2; ++f)
        acc[cf][f] = mfma16(vf, pf[f], acc[cf][f]);
    }
    __builtin_amdgcn_s_setprio(0);
  }

  // lsum: reduce over lq groups (different j within slab); lanes share i=lm
#pragma unroll
  for (int f = 0; f < 2; ++f) {
    float v = lsum[f];
    v += __shfl_xor(v, 16);
    v += __shfl_xor(v, 32);
    lsum[f] = v;
  }
  float* lsumlds = (float*)(smem + 65536);     // [4][32]
  float* invlds  = (float*)(smem + 66048);     // [32]
  if (ch == 0 && lq == 0) {
#pragma unroll
    for (int f = 0; f < 2; ++f) lsumlds[jw * 32 + f * 16 + lm] = lsum[f];
  }
  __syncthreads();   // PV(63) done; lsumlds visible; V region reusable

  // 4-way j-slab reduce into olds[32 i][256 c] fp32 (32 KB overlay)
  float* olds = (float*)smem;
#pragma unroll 1
  for (int rnd = 0; rnd < 4; ++rnd) {
    if (jw == rnd) {
#pragma unroll
      for (int cf = 0; cf < 8; ++cf)
#pragma unroll
        for (int f = 0; f < 2; ++f) {
          const int ii = f * 16 + lm;
          const int g  = ch * 32 + cf * 4 + lq;     // float4 granule 0..63
          float* dst = olds + ii * 256 + ((g ^ lm) << 2);
          if (rnd == 0) {
            *(floatx4*)dst = acc[cf][f];
          } else {
            floatx4 ov = *(const floatx4*)dst;
            ov = ov + acc[cf][f];
            *(floatx4*)dst = ov;
          }
        }
    }
    __syncthreads();
  }

  if (tid < 32)
    invlds[tid] = 1.0f / (lsumlds[tid] + lsumlds[32 + tid] +
                          lsumlds[64 + tid] + lsumlds[96 + tid]);
  __syncthreads();

  // epilogue: coalesced float4 over i (4 passes x 2048 floats)
  const float gm = gamma_p[0];
#pragma unroll
  for (int pass = 0; pass < 4; ++pass) {
    const int c  = pass * 64 + (tid >> 3);
    const int i4 = (tid & 7) * 4;
    floatx4 ov;
#pragma unroll
    for (int e = 0; e < 4; ++e) {
      const int ii = i4 + e;
      ov[e] = olds[ii * 256 + (((c >> 2) ^ (ii & 15)) << 2) + (c & 3)];
    }
    const floatx4 iv = *(const floatx4*)(invlds + i4);
    const size_t idx = (size_t)(b * CCH + c) * NN + i0 + i4;
    const floatx4 xv = *(const floatx4*)(x + idx);
    floatx4 o;
#pragma unroll
    for (int e = 0; e < 4; ++e)
      o[e] = gm * sat(ov[e] * iv[e]) + xv[e];
    *(floatx4*)(out + idx) = o;
  }
}

extern "C" void kernel_launch(void* const* d_in, const int* in_sizes, int n_in,
                              void* d_out, int out_size, void* d_ws, size_t ws_size,
                              hipStream_t stream) {
  (void)in_sizes; (void)n_in; (void)out_size; (void)ws_size;
  const float* x     = (const float*)d_in[0];
  const float* Wq    = (const float*)d_in[1];
  const float* bq    = (const float*)d_in[2];
  const float* Wk    = (const float*)d_in[3];
  const float* bk    = (const float*)d_in[4];
  const float* Wv    = (const float*)d_in[5];
  const float* bv    = (const float*)d_in[6];
  const float* gamma = (const float*)d_in[7];

  unsigned short* qT = (unsigned short*)d_ws;              // 1 MiB
  unsigned short* kT = qT + (size_t)NB * NN * CRD;         // 1 MiB
  unsigned short* vv = kT + (size_t)NB * NN * CRD;         // 8 MiB

  gemm_qkv_fused<<<dim3(64, 2, 4), 256, 0, stream>>>(x, Wq, bq, Wk, bk, Wv, bv,
                                                     qT, kT, vv);
  attn_kernel<<<dim3(512, 1, 1), 512, 0, stream>>>(x, gamma, qT, kT, vv,
                                                   (float*)d_out);
}